// Round 2
// baseline (11566.656 us; speedup 1.0000x reference)
//
#include <hip/hip_runtime.h>
#include <stdint.h>

typedef unsigned short u16;
typedef __attribute__((ext_vector_type(4))) float f32x4;
typedef __attribute__((ext_vector_type(8))) short bf16x8;

#define DEV __device__ __forceinline__
#define NWG 64

DEV u16 f2bf(float f) {
  union { float f; uint32_t u; } v; v.f = f;
  uint32_t r = (v.u + 0x7FFFu + ((v.u >> 16) & 1u)) >> 16;  // RNE
  return (u16)r;
}
DEV float bf2f(u16 h) {
  union { uint32_t u; float f; } v; v.u = ((uint32_t)h) << 16;
  return v.f;
}
DEV float sigmoidf(float x) { return 1.0f / (1.0f + expf(-x)); }

// async global->LDS, 16B per lane; lds base must be wave-uniform (HW adds lane*16)
DEV void gll16(const void* g, void* l) {
  __builtin_amdgcn_global_load_lds((__attribute__((address_space(1))) void*)g,
                                   (__attribute__((address_space(3))) void*)l,
                                   16, 0, 0);
}

// ---------------------------------------------------------------------------
// prep kernels
// ---------------------------------------------------------------------------
__global__ void convert_bf16_kernel(const float* __restrict__ in, u16* __restrict__ out, int n) {
  int i = (blockIdx.x * blockDim.x + threadIdx.x) * 4;
  if (i + 3 < n) {
    f32x4 v = *(const f32x4*)(in + i);
    uint64_t pk = (uint64_t)f2bf(v[0]) | ((uint64_t)f2bf(v[1]) << 16) |
                  ((uint64_t)f2bf(v[2]) << 32) | ((uint64_t)f2bf(v[3]) << 48);
    *(uint64_t*)(out + i) = pk;
  }
}

// out(C,R) bf16 = transpose(in(R,C) f32); R,C multiples of 32
__global__ __launch_bounds__(1024) void transpose_to_bf16(
    const float* __restrict__ in, u16* __restrict__ out, int R, int C) {
  __shared__ float tl[32][33];
  const int tx = threadIdx.x, ty = threadIdx.y;
  const int c0 = blockIdx.x * 32, r0 = blockIdx.y * 32;
  tl[ty][tx] = in[(size_t)(r0 + ty) * C + c0 + tx];
  __syncthreads();
  out[(size_t)(c0 + ty) * R + r0 + tx] = f2bf(tl[tx][ty]);
}

// ---------------------------------------------------------------------------
// GEMM: C(MxN) = A(MxK,bf16) @ Bt(NxK,bf16)^T   (m97 structure, 128x128, BK=64)
// mode 0: write Cf(f32) + Cb(bf16), no bias   (skip projection -> seq)
// mode 1: write Cb(bf16), +bias               (xg, bf16 storage)
// mode 2: write Cf(f32), +bias                (xg, f32 storage)
// ---------------------------------------------------------------------------
__global__ __launch_bounds__(256) void gemm_bt_kernel(
    const u16* __restrict__ A, const u16* __restrict__ Bt,
    const float* __restrict__ bias,
    float* __restrict__ Cf, u16* __restrict__ Cb,
    int M, int N, int K, int mode) {
  __shared__ u16 As[128 * 64];
  __shared__ u16 Bs[128 * 64];
  const int tid  = threadIdx.x;
  const int lane = tid & 63;
  const int wid  = tid >> 6;
  const int wr   = wid >> 1, wc = wid & 1;
  const size_t arow0 = (size_t)blockIdx.y * 128;
  const size_t brow0 = (size_t)blockIdx.x * 128;

  f32x4 acc[4][4];
#pragma unroll
  for (int m = 0; m < 4; ++m)
#pragma unroll
    for (int n = 0; n < 4; ++n) acc[m][n] = (f32x4){0.f, 0.f, 0.f, 0.f};

  for (int k0 = 0; k0 < K; k0 += 64) {
#pragma unroll
    for (int it = 0; it < 4; ++it) {
      const int slot = it * 4 + wid;         // wave-uniform
      const int ch   = slot * 64 + lane;     // 16B chunk id (0..1023)
      const int r    = ch >> 3;
      const int cc   = (ch & 7) * 8;
      gll16(A  + (arow0 + r) * K + k0 + cc, (void*)(As + slot * 64 * 8));
      gll16(Bt + (brow0 + r) * K + k0 + cc, (void*)(Bs + slot * 64 * 8));
    }
    __syncthreads();   // drains vmcnt (gll) too
#pragma unroll
    for (int kk = 0; kk < 2; ++kk) {
      const int ro = lane & 15;
      const int ko = kk * 32 + (lane >> 4) * 8;
      bf16x8 av[4], bv[4];
#pragma unroll
      for (int m = 0; m < 4; ++m) av[m] = *(const bf16x8*)(As + (wr * 64 + m * 16 + ro) * 64 + ko);
#pragma unroll
      for (int n = 0; n < 4; ++n) bv[n] = *(const bf16x8*)(Bs + (wc * 64 + n * 16 + ro) * 64 + ko);
#pragma unroll
      for (int m = 0; m < 4; ++m)
#pragma unroll
        for (int n = 0; n < 4; ++n)
          acc[m][n] = __builtin_amdgcn_mfma_f32_16x16x32_bf16(av[m], bv[n], acc[m][n], 0, 0, 0);
    }
    __syncthreads();
  }

  const int rb = (lane >> 4) * 4;
  const int cn = lane & 15;
#pragma unroll
  for (int m = 0; m < 4; ++m) {
#pragma unroll
    for (int n = 0; n < 4; ++n) {
      const size_t col = brow0 + wc * 64 + n * 16 + cn;
      const float badd = (mode != 0) ? bias[col] : 0.f;
#pragma unroll
      for (int r = 0; r < 4; ++r) {
        const size_t row = arow0 + wr * 64 + m * 16 + rb + r;
        const float v = acc[m][n][r] + badd;
        if (mode == 0) { Cf[row * N + col] = v; Cb[row * N + col] = f2bf(v); }
        else if (mode == 1) { Cb[row * N + col] = f2bf(v); }
        else { Cf[row * N + col] = v; }
      }
    }
  }
}

// ---------------------------------------------------------------------------
// Persistent per-layer LSTM recurrence. 64 WGs x 256 thr, 1 WG/CU (160KB LDS).
// WG owns 16 units (all 4 gates). Wr slice resident in LDS (128KB, swizzled).
// Per step: h_{t-1} staged in 4 ping-pong chunks (2x16KB), MFMA 16x16x32,
// fused gates/cell update (c in registers), h_t -> ys (bf16), grid sync via
// per-step device-scope counter (fence release/acquire for cross-XCD vis).
// ---------------------------------------------------------------------------
__global__ __launch_bounds__(256) void lstm_layer_kernel(
    const u16* __restrict__ xgb, const float* __restrict__ xgf, int xg32,
    const u16* __restrict__ wrT,      // (4096,1024) bf16, layer slice
    u16* __restrict__ ys,             // (B*T,1024) bf16; h_t at row b*256+t
    float* __restrict__ out,          // (2,L,B,U) f32
    uint32_t* __restrict__ cnt,       // [256] zeroed per launch
    int l) {
  __shared__ __align__(16) u16 Ws[64 * 1024];    // 128 KB
  __shared__ __align__(16) u16 Hs[2][32 * 256];  // 2 x 16 KB ping-pong
  float* gl = (float*)&Hs[0][0];                 // [4][32][16] f32, aliased

  const int tid  = threadIdx.x;
  const int lane = tid & 63;
  const int w    = tid >> 6;          // gate id
  const int u0   = blockIdx.x * 16;
  const int r0   = lane & 15;
  const int hi   = lane >> 4;
  const int rb   = hi * 4;

  // ---- one-time: Wr slice -> LDS (source-side swizzle, linear dest) ----
  for (int it = 0; it < 32; ++it) {
    const int slot = it * 4 + w;          // wave-uniform
    const int ch   = slot * 64 + lane;    // 0..8191 chunk id
    const int r    = ch >> 7;             // LDS row 0..63
    const int q    = (ch & 127) ^ (r & 7);
    const int gate = r >> 4, j = r & 15;
    gll16(wrT + ((size_t)(gate * 1024 + u0 + j)) * 1024 + q * 8,
          (void*)(Ws + slot * 64 * 8));
  }

  float c0 = 0.f, c1 = 0.f;            // cell state, 2 (b,j) items per thread
  __syncthreads();                      // Ws ready (drains vmcnt)

  for (int t = 0; t < 256; ++t) {
    // xg loads issued early (latency hides under staging+MFMA)
    float xv[8];
    {
      const size_t gcol = (size_t)w * 1024 + u0 + r0;
#pragma unroll
      for (int m = 0; m < 2; ++m)
#pragma unroll
        for (int r = 0; r < 4; ++r) {
          const size_t off = ((size_t)((m * 16 + rb + r) * 256 + t)) * 4096 + gcol;
          xv[m * 4 + r] = xg32 ? xgf[off] : bf2f(xgb[off]);
        }
    }

    f32x4 acc0 = (f32x4){0.f, 0.f, 0.f, 0.f};
    f32x4 acc1 = acc0;

    if (t > 0) {
      // stage chunk 0 into Hs[0]
#pragma unroll
      for (int it = 0; it < 4; ++it) {
        const int slot = it * 4 + w;
        const int ch   = slot * 64 + lane;   // 0..1023
        const int r    = ch >> 5;            // batch 0..31
        const int q    = (ch & 31) ^ (r & 7);
        gll16(ys + ((size_t)(r * 256 + t - 1)) * 1024 + q * 8,
              (void*)(&Hs[0][0] + slot * 64 * 8));
      }
      for (int c = 0; c < 4; ++c) {
        __syncthreads();                     // chunk c staged (vmcnt drained)
        if (c < 3) {                         // prefetch chunk c+1 (overlaps MFMA)
          const int nb = (c + 1) & 1;
#pragma unroll
          for (int it = 0; it < 4; ++it) {
            const int slot = it * 4 + w;
            const int ch   = slot * 64 + lane;
            const int r    = ch >> 5;
            const int q    = (ch & 31) ^ (r & 7);
            gll16(ys + ((size_t)(r * 256 + t - 1)) * 1024 + (c + 1) * 256 + q * 8,
                  (void*)(&Hs[nb][0] + slot * 64 * 8));
          }
        }
        const u16* Hb = &Hs[c & 1][0];
#pragma unroll
        for (int kk = 0; kk < 8; ++kk) {
          const int qb  = kk * 4 + hi;                     // chunk-local 16B col
          const int swA = (qb ^ (r0 & 7)) * 8;
          bf16x8 a0 = *(const bf16x8*)(Hb + r0 * 256 + swA);
          bf16x8 a1 = *(const bf16x8*)(Hb + (16 + r0) * 256 + swA);
          const int qw  = c * 32 + qb;                     // global 16B col 0..127
          const int swB = (qw ^ (r0 & 7)) * 8;
          bf16x8 b0 = *(const bf16x8*)(Ws + (w * 16 + r0) * 1024 + swB);
          acc0 = __builtin_amdgcn_mfma_f32_16x16x32_bf16(a0, b0, acc0, 0, 0, 0);
          acc1 = __builtin_amdgcn_mfma_f32_16x16x32_bf16(a1, b0, acc1, 0, 0, 0);
        }
      }
      __syncthreads();   // all waves done reading Hs before gl (alias) write
    }

    // D frag -> gl: col=lane&15 (unit j), row=(lane>>4)*4+reg (batch)
#pragma unroll
    for (int m = 0; m < 2; ++m) {
      f32x4 a = m ? acc1 : acc0;
#pragma unroll
      for (int r = 0; r < 4; ++r)
        gl[((w * 32) + m * 16 + rb + r) * 16 + r0] = a[r] + xv[m * 4 + r];
    }
    __syncthreads();

    // gates + cell update (c in regs) + h store
#pragma unroll
    for (int pp = 0; pp < 2; ++pp) {
      const int p  = tid + pp * 256;
      const int b_ = p >> 4, j = p & 15;
      const float gi = gl[(0  + b_) * 16 + j];
      const float gf = gl[(32 + b_) * 16 + j];
      const float gc = gl[(64 + b_) * 16 + j];
      const float go = gl[(96 + b_) * 16 + j];
      const float i_ = sigmoidf(gi), f_ = sigmoidf(gf);
      const float cd = tanhf(gc),   o_ = sigmoidf(go);
      float& c = pp ? c1 : c0;
      c = f_ * c + i_ * cd;                       // t=0: c starts 0 -> i*cd
      const float h = o_ * tanhf(c);
      ys[((size_t)(b_ * 256 + t)) * 1024 + u0 + j] = f2bf(h);
      if (t == 255) {
        out[(size_t)l * 32768 + (size_t)b_ * 1024 + u0 + j]       = h;
        out[(size_t)(4 + l) * 32768 + (size_t)b_ * 1024 + u0 + j] = c;
      }
    }

    // grid sync: publish h_t agent-wide, wait for all 64 WGs
    if (t < 255) {
      __syncthreads();   // drain all threads' h stores to L2
      if (tid == 0) {
        __builtin_amdgcn_fence(__ATOMIC_RELEASE, "agent");   // wb L2 -> IC
        __hip_atomic_fetch_add(cnt + t, 1u, __ATOMIC_RELAXED, __HIP_MEMORY_SCOPE_AGENT);
        while (__hip_atomic_load(cnt + t, __ATOMIC_RELAXED, __HIP_MEMORY_SCOPE_AGENT) < NWG) {}
        __builtin_amdgcn_fence(__ATOMIC_ACQUIRE, "agent");   // inv L1/L2
      }
      __syncthreads();
    }
  }
}

// seq += ys (residual); refresh bf16 copy of seq
__global__ void seq_update_kernel(float* __restrict__ seqf, u16* __restrict__ seqb,
                                  const u16* __restrict__ ys, int n) {
  int i = (blockIdx.x * blockDim.x + threadIdx.x) * 4;
  if (i + 3 < n) {
    f32x4 s = *(f32x4*)(seqf + i);
    uint64_t yv = *(const uint64_t*)(ys + i);
    s[0] += bf2f((u16)(yv & 0xFFFF));
    s[1] += bf2f((u16)((yv >> 16) & 0xFFFF));
    s[2] += bf2f((u16)((yv >> 32) & 0xFFFF));
    s[3] += bf2f((u16)((yv >> 48) & 0xFFFF));
    *(f32x4*)(seqf + i) = s;
    uint64_t pk = (uint64_t)f2bf(s[0]) | ((uint64_t)f2bf(s[1]) << 16) |
                  ((uint64_t)f2bf(s[2]) << 32) | ((uint64_t)f2bf(s[3]) << 48);
    *(uint64_t*)(seqb + i) = pk;
  }
}

// ---------------------------------------------------------------------------
extern "C" void kernel_launch(void* const* d_in, const int* in_sizes, int n_in,
                              void* d_out, int out_size, void* d_ws, size_t ws_size,
                              hipStream_t stream) {
  const float* x     = (const float*)d_in[0];   // (32,256,512)
  const float* Wskip = (const float*)d_in[1];   // (512,1024)
  const float* Wk    = (const float*)d_in[2];   // (4,1024,4096)
  const float* Wr    = (const float*)d_in[3];   // (4,1024,4096)
  const float* bias  = (const float*)d_in[4];   // (4,4096)
  float* out = (float*)d_out;

  char* ws = (char*)d_ws;
  size_t o = 0;
  auto carve = [&](size_t bytes) -> char* {
    char* p = ws + o;
    o += (bytes + 255) & ~(size_t)255;
    return p;
  };
  u16*      xbf  = (u16*)     carve((size_t)8192 * 512 * 2);
  u16*      wskT = (u16*)     carve((size_t)1024 * 512 * 2);
  u16*      wkT  = (u16*)     carve((size_t)4 * 4096 * 1024 * 2);
  u16*      wrT  = (u16*)     carve((size_t)4 * 4096 * 1024 * 2);
  float*    seqf = (float*)   carve((size_t)8192 * 1024 * 4);
  u16*      seqb = (u16*)     carve((size_t)8192 * 1024 * 2);
  u16*      ysb  = (u16*)     carve((size_t)8192 * 1024 * 2);
  uint32_t* cnt  = (uint32_t*)carve((size_t)256 * 4);
  // xg: prefer f32 storage (accuracy) if workspace allows
  const int xg32 = (ws_size >= o + (size_t)8192 * 4096 * 4 + 512) ? 1 : 0;
  float* xgf = nullptr;
  u16*   xgb = nullptr;
  if (xg32) xgf = (float*)carve((size_t)8192 * 4096 * 4);
  else      xgb = (u16*)  carve((size_t)8192 * 4096 * 2);

  // ---- prep: bf16 conversions / weight transposes ----
  convert_bf16_kernel<<<4096, 256, 0, stream>>>(x, xbf, 8192 * 512);
  dim3 tb(32, 32);
  transpose_to_bf16<<<dim3(1024 / 32, 512 / 32), tb, 0, stream>>>(Wskip, wskT, 512, 1024);
  for (int l = 0; l < 4; ++l) {
    transpose_to_bf16<<<dim3(4096 / 32, 1024 / 32), tb, 0, stream>>>(
        Wk + (size_t)l * 1024 * 4096, wkT + (size_t)l * 4096 * 1024, 1024, 4096);
    transpose_to_bf16<<<dim3(4096 / 32, 1024 / 32), tb, 0, stream>>>(
        Wr + (size_t)l * 1024 * 4096, wrT + (size_t)l * 4096 * 1024, 1024, 4096);
  }

  // ---- skip projection: seq = x @ W_skip ----
  gemm_bt_kernel<<<dim3(1024 / 128, 8192 / 128), 256, 0, stream>>>(
      xbf, wskT, nullptr, seqf, seqb, 8192, 1024, 512, 0);

  // ---- layers ----
  for (int l = 0; l < 4; ++l) {
    gemm_bt_kernel<<<dim3(4096 / 128, 8192 / 128), 256, 0, stream>>>(
        seqb, wkT + (size_t)l * 4096 * 1024, bias + (size_t)l * 4096,
        xgf, xgb, 8192, 4096, 1024, xg32 ? 2 : 1);
    hipMemsetAsync(cnt, 0, 256 * 4, stream);
    lstm_layer_kernel<<<NWG, 256, 0, stream>>>(xgb, xgf, xg32,
                                               wrT + (size_t)l * 4096 * 1024,
                                               ysb, out, cnt, l);
    if (l < 3)
      seq_update_kernel<<<8192, 256, 0, stream>>>(seqf, seqb, ysb, 8192 * 1024);
  }
}

// Round 3
// 6782.511 us; speedup vs baseline: 1.7054x; 1.7054x over previous
//
#include <hip/hip_runtime.h>
#include <stdint.h>

typedef unsigned short u16;
typedef __attribute__((ext_vector_type(4))) float f32x4;
typedef __attribute__((ext_vector_type(8))) short bf16x8;

#define DEV __device__ __forceinline__
#define NWG 64

DEV u16 f2bf(float f) {
  union { float f; uint32_t u; } v; v.f = f;
  uint32_t r = (v.u + 0x7FFFu + ((v.u >> 16) & 1u)) >> 16;  // RNE
  return (u16)r;
}
DEV float bf2f(u16 h) {
  union { uint32_t u; float f; } v; v.u = ((uint32_t)h) << 16;
  return v.f;
}
DEV float sigmoidf(float x) { return 1.0f / (1.0f + expf(-x)); }

// async global->LDS, 16B per lane; lds base must be wave-uniform (HW adds lane*16)
DEV void gll16(const void* g, void* l) {
  __builtin_amdgcn_global_load_lds((__attribute__((address_space(1))) void*)g,
                                   (__attribute__((address_space(3))) void*)l,
                                   16, 0, 0);
}

// coherent 16B load: sc0 sc1 bypass L1/L2, read fresh from IC (cross-XCD safe)
DEV f32x4 ldg_coh16(const u16* p) {
  f32x4 r;
  asm volatile("global_load_dwordx4 %0, %1, off sc0 sc1"
               : "=&v"(r) : "v"(p) : "memory");
  return r;
}

// ---------------------------------------------------------------------------
// prep kernels
// ---------------------------------------------------------------------------
__global__ void convert_bf16_kernel(const float* __restrict__ in, u16* __restrict__ out, int n) {
  int i = (blockIdx.x * blockDim.x + threadIdx.x) * 4;
  if (i + 3 < n) {
    f32x4 v = *(const f32x4*)(in + i);
    uint64_t pk = (uint64_t)f2bf(v[0]) | ((uint64_t)f2bf(v[1]) << 16) |
                  ((uint64_t)f2bf(v[2]) << 32) | ((uint64_t)f2bf(v[3]) << 48);
    *(uint64_t*)(out + i) = pk;
  }
}

// out(C,R) bf16 = transpose(in(R,C) f32); R,C multiples of 32
__global__ __launch_bounds__(1024) void transpose_to_bf16(
    const float* __restrict__ in, u16* __restrict__ out, int R, int C) {
  __shared__ float tl[32][33];
  const int tx = threadIdx.x, ty = threadIdx.y;
  const int c0 = blockIdx.x * 32, r0 = blockIdx.y * 32;
  tl[ty][tx] = in[(size_t)(r0 + ty) * C + c0 + tx];
  __syncthreads();
  out[(size_t)(c0 + ty) * R + r0 + tx] = f2bf(tl[tx][ty]);
}

// ---------------------------------------------------------------------------
// GEMM: C(MxN) = A(MxK,bf16) @ Bt(NxK,bf16)^T   (m97 structure, 128x128, BK=64)
// ---------------------------------------------------------------------------
__global__ __launch_bounds__(256) void gemm_bt_kernel(
    const u16* __restrict__ A, const u16* __restrict__ Bt,
    const float* __restrict__ bias,
    float* __restrict__ Cf, u16* __restrict__ Cb,
    int M, int N, int K, int mode) {
  __shared__ u16 As[128 * 64];
  __shared__ u16 Bs[128 * 64];
  const int tid  = threadIdx.x;
  const int lane = tid & 63;
  const int wid  = tid >> 6;
  const int wr   = wid >> 1, wc = wid & 1;
  const size_t arow0 = (size_t)blockIdx.y * 128;
  const size_t brow0 = (size_t)blockIdx.x * 128;

  f32x4 acc[4][4];
#pragma unroll
  for (int m = 0; m < 4; ++m)
#pragma unroll
    for (int n = 0; n < 4; ++n) acc[m][n] = (f32x4){0.f, 0.f, 0.f, 0.f};

  for (int k0 = 0; k0 < K; k0 += 64) {
#pragma unroll
    for (int it = 0; it < 4; ++it) {
      const int slot = it * 4 + wid;
      const int ch   = slot * 64 + lane;
      const int r    = ch >> 3;
      const int cc   = (ch & 7) * 8;
      gll16(A  + (arow0 + r) * K + k0 + cc, (void*)(As + slot * 64 * 8));
      gll16(Bt + (brow0 + r) * K + k0 + cc, (void*)(Bs + slot * 64 * 8));
    }
    __syncthreads();
#pragma unroll
    for (int kk = 0; kk < 2; ++kk) {
      const int ro = lane & 15;
      const int ko = kk * 32 + (lane >> 4) * 8;
      bf16x8 av[4], bv[4];
#pragma unroll
      for (int m = 0; m < 4; ++m) av[m] = *(const bf16x8*)(As + (wr * 64 + m * 16 + ro) * 64 + ko);
#pragma unroll
      for (int n = 0; n < 4; ++n) bv[n] = *(const bf16x8*)(Bs + (wc * 64 + n * 16 + ro) * 64 + ko);
#pragma unroll
      for (int m = 0; m < 4; ++m)
#pragma unroll
        for (int n = 0; n < 4; ++n)
          acc[m][n] = __builtin_amdgcn_mfma_f32_16x16x32_bf16(av[m], bv[n], acc[m][n], 0, 0, 0);
    }
    __syncthreads();
  }

  const int rb = (lane >> 4) * 4;
  const int cn = lane & 15;
#pragma unroll
  for (int m = 0; m < 4; ++m) {
#pragma unroll
    for (int n = 0; n < 4; ++n) {
      const size_t col = brow0 + wc * 64 + n * 16 + cn;
      const float badd = (mode != 0) ? bias[col] : 0.f;
#pragma unroll
      for (int r = 0; r < 4; ++r) {
        const size_t row = arow0 + wr * 64 + m * 16 + rb + r;
        const float v = acc[m][n][r] + badd;
        if (mode == 0) { Cf[row * N + col] = v; Cb[row * N + col] = f2bf(v); }
        else if (mode == 1) { Cb[row * N + col] = f2bf(v); }
        else { Cf[row * N + col] = v; }
      }
    }
  }
}

// ---------------------------------------------------------------------------
// Persistent per-layer LSTM recurrence, fence-free coherent h exchange.
// 64 WGs x 256 thr, 1 WG/CU. WG owns 16 units x 4 gates; Wr slice in LDS.
// h published via sc1 write-through stores; flags[wg] monotone counter;
// spin = 64-lane coherent flag load + __all; h re-read via sc0/sc1 dwordx4.
// ---------------------------------------------------------------------------
__global__ __launch_bounds__(256) void lstm_layer_kernel(
    const u16* __restrict__ xgb, const float* __restrict__ xgf, int xg32,
    const u16* __restrict__ wrT,      // (4096,1024) bf16, layer slice
    u16* __restrict__ ys,             // (B*T,1024) bf16; h_t at row b*256+t
    float* __restrict__ out,          // (2,L,B,U) f32
    uint32_t* __restrict__ flags,     // [64], zeroed once per launch
    int l) {
  __shared__ __align__(16) u16 Ws[64 * 1024];    // 128 KB
  __shared__ __align__(16) u16 Hs[2][32 * 256];  // 2 x 16 KB ping-pong
  float* gl = (float*)&Hs[0][0];                 // [4][32][16] f32, aliased

  const int tid  = threadIdx.x;
  const int lane = tid & 63;
  const int w    = tid >> 6;          // gate id
  const int u0   = blockIdx.x * 16;
  const int r0   = lane & 15;
  const int hi   = lane >> 4;
  const int rb   = hi * 4;
  const int gb   = tid >> 3;          // gate-phase batch row 0..31
  const int j0   = (tid & 7) * 2;     // gate-phase unit pair

  // ---- one-time: Wr slice -> LDS (source-side swizzle, linear dest) ----
  for (int it = 0; it < 32; ++it) {
    const int slot = it * 4 + w;          // wave-uniform
    const int ch   = slot * 64 + lane;    // 0..8191 chunk id
    const int r    = ch >> 7;             // LDS row 0..63
    const int q    = (ch & 127) ^ (r & 7);
    const int gate = r >> 4, j = r & 15;
    gll16(wrT + ((size_t)(gate * 1024 + u0 + j)) * 1024 + q * 8,
          (void*)(Ws + slot * 64 * 8));
  }

  float c0 = 0.f, c1 = 0.f;            // cell state for (gb,j0),(gb,j0+1)
  __syncthreads();                      // Ws ready (drains vmcnt)

  for (int t = 0; t < 256; ++t) {
    // xg loads first (independent of h; latency hides under spin+staging)
    float xv[8];
    {
      const size_t gcol = (size_t)w * 1024 + u0 + r0;
#pragma unroll
      for (int m = 0; m < 2; ++m)
#pragma unroll
        for (int r = 0; r < 4; ++r) {
          const size_t off = ((size_t)((m * 16 + rb + r) * 256 + t)) * 4096 + gcol;
          xv[m * 4 + r] = xg32 ? xgf[off] : bf2f(xgb[off]);
        }
    }

    f32x4 acc0 = (f32x4){0.f, 0.f, 0.f, 0.f};
    f32x4 acc1 = acc0;

    if (t > 0) {
      // ---- wait for all WGs' h_{t-1} (monotone flags, no RMW) ----
      const uint32_t target = (uint32_t)(l * 256 + t);
      while (true) {
        uint32_t v = __hip_atomic_load(flags + lane, __ATOMIC_RELAXED,
                                       __HIP_MEMORY_SCOPE_AGENT);
        if (__all(v >= target)) break;
        __builtin_amdgcn_s_sleep(1);
      }

      // ---- coherent read of full h_{t-1} (64 KB) into regs ----
      f32x4 hreg[16];
#pragma unroll
      for (int k = 0; k < 16; ++k) {
        const int c   = k >> 2;                 // chunk 0..3 (256 cols each)
        const int s   = (k & 3) * 256 + tid;    // 16B slot in chunk
        const int row = s >> 5;                 // batch 0..31
        const int q   = (s & 31) ^ (row & 7);   // source-side swizzle
        hreg[k] = ldg_coh16(ys + ((size_t)(row * 256 + t - 1)) * 1024 + c * 256 + q * 8);
      }
      asm volatile("s_waitcnt vmcnt(0)" ::: "memory");

#pragma unroll
      for (int half = 0; half < 2; ++half) {
        // ds_write 2 chunks into ping-pong buffers
#pragma unroll
        for (int k = half * 8; k < half * 8 + 8; ++k) {
          const int s = (k & 3) * 256 + tid;
          *(f32x4*)(&Hs[(k >> 2) & 1][0] + s * 8) = hreg[k];
        }
        __syncthreads();
#pragma unroll
        for (int cc = 0; cc < 2; ++cc) {
          const int cg = half * 2 + cc;          // global chunk 0..3
          const u16* Hb = &Hs[cc][0];
#pragma unroll
          for (int kk = 0; kk < 8; ++kk) {
            const int qb  = kk * 4 + hi;
            const int swA = (qb ^ (r0 & 7)) * 8;
            bf16x8 a0 = *(const bf16x8*)(Hb + r0 * 256 + swA);
            bf16x8 a1 = *(const bf16x8*)(Hb + (16 + r0) * 256 + swA);
            const int qw  = cg * 32 + qb;
            const int swB = (qw ^ (r0 & 7)) * 8;
            bf16x8 b0 = *(const bf16x8*)(Ws + (w * 16 + r0) * 1024 + swB);
            acc0 = __builtin_amdgcn_mfma_f32_16x16x32_bf16(a0, b0, acc0, 0, 0, 0);
            acc1 = __builtin_amdgcn_mfma_f32_16x16x32_bf16(a1, b0, acc1, 0, 0, 0);
          }
        }
        __syncthreads();   // waves done reading Hs before rewrite / gl alias
      }
    }

    // D frag -> gl: col=lane&15 (unit j), row=(lane>>4)*4+reg (batch)
#pragma unroll
    for (int m = 0; m < 2; ++m) {
      f32x4 a = m ? acc1 : acc0;
#pragma unroll
      for (int r = 0; r < 4; ++r)
        gl[((w * 32) + m * 16 + rb + r) * 16 + r0] = a[r] + xv[m * 4 + r];
    }
    __syncthreads();

    // gates + cell update (c in regs) + coherent h publish (u32 pairs)
    float hv[2];
#pragma unroll
    for (int jj = 0; jj < 2; ++jj) {
      const int j = j0 + jj;
      const float gi = gl[(0  + gb) * 16 + j];
      const float gf = gl[(32 + gb) * 16 + j];
      const float gc = gl[(64 + gb) * 16 + j];
      const float go = gl[(96 + gb) * 16 + j];
      const float i_ = sigmoidf(gi), f_ = sigmoidf(gf);
      const float cd = tanhf(gc),   o_ = sigmoidf(go);
      float& c = jj ? c1 : c0;
      c = f_ * c + i_ * cd;
      hv[jj] = o_ * tanhf(c);
      if (t == 255) {
        out[(size_t)l * 32768 + (size_t)gb * 1024 + u0 + j]       = hv[jj];
        out[(size_t)(4 + l) * 32768 + (size_t)gb * 1024 + u0 + j] = c;
      }
    }
    const uint32_t pk = (uint32_t)f2bf(hv[0]) | ((uint32_t)f2bf(hv[1]) << 16);
    __hip_atomic_store((uint32_t*)(ys + ((size_t)(gb * 256 + t)) * 1024 + u0 + j0),
                       pk, __ATOMIC_RELAXED, __HIP_MEMORY_SCOPE_AGENT);

    if (t < 255) {
      __syncthreads();   // emits s_waitcnt vmcnt(0): all waves' h stores at IC
      if (tid == 0)
        __hip_atomic_store(flags + blockIdx.x, (uint32_t)(l * 256 + t + 1),
                           __ATOMIC_RELAXED, __HIP_MEMORY_SCOPE_AGENT);
      __syncthreads();   // gl (Hs alias) safe to reuse next step
    }
  }
}

// seq += ys (residual); refresh bf16 copy of seq
__global__ void seq_update_kernel(float* __restrict__ seqf, u16* __restrict__ seqb,
                                  const u16* __restrict__ ys, int n) {
  int i = (blockIdx.x * blockDim.x + threadIdx.x) * 4;
  if (i + 3 < n) {
    f32x4 s = *(f32x4*)(seqf + i);
    uint64_t yv = *(const uint64_t*)(ys + i);
    s[0] += bf2f((u16)(yv & 0xFFFF));
    s[1] += bf2f((u16)((yv >> 16) & 0xFFFF));
    s[2] += bf2f((u16)((yv >> 32) & 0xFFFF));
    s[3] += bf2f((u16)((yv >> 48) & 0xFFFF));
    *(f32x4*)(seqf + i) = s;
    uint64_t pk = (uint64_t)f2bf(s[0]) | ((uint64_t)f2bf(s[1]) << 16) |
                  ((uint64_t)f2bf(s[2]) << 32) | ((uint64_t)f2bf(s[3]) << 48);
    *(uint64_t*)(seqb + i) = pk;
  }
}

// ---------------------------------------------------------------------------
extern "C" void kernel_launch(void* const* d_in, const int* in_sizes, int n_in,
                              void* d_out, int out_size, void* d_ws, size_t ws_size,
                              hipStream_t stream) {
  const float* x     = (const float*)d_in[0];   // (32,256,512)
  const float* Wskip = (const float*)d_in[1];   // (512,1024)
  const float* Wk    = (const float*)d_in[2];   // (4,1024,4096)
  const float* Wr    = (const float*)d_in[3];   // (4,1024,4096)
  const float* bias  = (const float*)d_in[4];   // (4,4096)
  float* out = (float*)d_out;

  char* ws = (char*)d_ws;
  size_t o = 0;
  auto carve = [&](size_t bytes) -> char* {
    char* p = ws + o;
    o += (bytes + 255) & ~(size_t)255;
    return p;
  };
  u16*      xbf   = (u16*)     carve((size_t)8192 * 512 * 2);
  u16*      wskT  = (u16*)     carve((size_t)1024 * 512 * 2);
  u16*      wkT   = (u16*)     carve((size_t)4 * 4096 * 1024 * 2);
  u16*      wrT   = (u16*)     carve((size_t)4 * 4096 * 1024 * 2);
  float*    seqf  = (float*)   carve((size_t)8192 * 1024 * 4);
  u16*      seqb  = (u16*)     carve((size_t)8192 * 1024 * 2);
  u16*      ysb   = (u16*)     carve((size_t)8192 * 1024 * 2);
  uint32_t* flags = (uint32_t*)carve((size_t)64 * 4);
  // xg: prefer f32 storage (accuracy) if workspace allows
  const int xg32 = (ws_size >= o + (size_t)8192 * 4096 * 4 + 512) ? 1 : 0;
  float* xgf = nullptr;
  u16*   xgb = nullptr;
  if (xg32) xgf = (float*)carve((size_t)8192 * 4096 * 4);
  else      xgb = (u16*)  carve((size_t)8192 * 4096 * 2);

  // ---- prep ----
  hipMemsetAsync(flags, 0, 64 * 4, stream);
  convert_bf16_kernel<<<4096, 256, 0, stream>>>(x, xbf, 8192 * 512);
  dim3 tb(32, 32);
  transpose_to_bf16<<<dim3(1024 / 32, 512 / 32), tb, 0, stream>>>(Wskip, wskT, 512, 1024);
  for (int l = 0; l < 4; ++l) {
    transpose_to_bf16<<<dim3(4096 / 32, 1024 / 32), tb, 0, stream>>>(
        Wk + (size_t)l * 1024 * 4096, wkT + (size_t)l * 4096 * 1024, 1024, 4096);
    transpose_to_bf16<<<dim3(4096 / 32, 1024 / 32), tb, 0, stream>>>(
        Wr + (size_t)l * 1024 * 4096, wrT + (size_t)l * 4096 * 1024, 1024, 4096);
  }

  // ---- skip projection: seq = x @ W_skip ----
  gemm_bt_kernel<<<dim3(1024 / 128, 8192 / 128), 256, 0, stream>>>(
      xbf, wskT, nullptr, seqf, seqb, 8192, 1024, 512, 0);

  // ---- layers ----
  for (int l = 0; l < 4; ++l) {
    gemm_bt_kernel<<<dim3(4096 / 128, 8192 / 128), 256, 0, stream>>>(
        seqb, wkT + (size_t)l * 4096 * 1024, bias + (size_t)l * 4096,
        xgf, xgb, 8192, 4096, 1024, xg32 ? 2 : 1);
    lstm_layer_kernel<<<NWG, 256, 0, stream>>>(xgb, xgf, xg32,
                                               wrT + (size_t)l * 4096 * 1024,
                                               ysb, out, flags, l);
    if (l < 3)
      seq_update_kernel<<<8192, 256, 0, stream>>>(seqf, seqb, ysb, 8192 * 1024);
  }
}